// Round 4
// baseline (43218.106 us; speedup 1.0000x reference)
//
#include <hip/hip_runtime.h>
#include <cstdint>
#include <cstddef>

#define B_    64
#define T_    1024
#define D_    256
#define H_    512
#define BU_   512
#define GRID_ 256
#define NT_   512
// 8 independent batch groups; group g = the wave-index-g waves of ALL 256
// blocks (256 waves/group). Group g owns batch rows g*8..g*8+7, all 512 cols;
// per wave 2 cols (col0 = blockIdx*2). No __syncthreads in the main loop:
// all LDS buffers are wave-private, rows are partitioned by wave index, so
// the only sync needed is the per-group global barrier at wave scope.
// Each CU hosts 8 waves from 8 different streams (2 per SIMD): while one
// stream sleeps in its gen-poll, the others issue VALU -> barrier latency is
// hidden by cross-stream overlap, and phases self-stagger instead of 2048
// waves hitting each phase in lockstep.

__device__ __forceinline__ float fsigmoid(float x) { return 1.f / (1.f + __expf(-x)); }
__device__ __forceinline__ float ftanh(float x)    { return 2.f / (1.f + __expf(-2.f * x)) - 1.f; }

// Relaxed agent-scope atomic store: sc0/sc1 write-through, visible at L3 once
// vmcnt-drained, never dirty in any L2.
__device__ __forceinline__ void astore(float* p, float v) {
  union { float f; unsigned u; } c; c.f = v;
  __hip_atomic_store((unsigned*)p, c.u, __ATOMIC_RELAXED, __HIP_MEMORY_SCOPE_AGENT);
}

// Relaxed agent-scope 8B atomic load: bypasses L1/L2, reads L3 directly ->
// always fresh, no buffer_inv needed anywhere.
__device__ __forceinline__ float2 aload2(const float* p) {
  unsigned long long u = __hip_atomic_load((const unsigned long long*)p,
                                           __ATOMIC_RELAXED, __HIP_MEMORY_SCOPE_AGENT);
  union { unsigned long long u; float2 f; } c; c.u = u;
  return c.f;
}
__device__ __forceinline__ float4 aload4(const float* p) {
  float2 a = aload2(p);
  float2 b = aload2(p + 2);
  return make_float4(a.x, a.y, b.x, b.y);
}

// Wave-scope fence-free group barrier over 256 waves (one per block).
// Monotonic counters: 16 leaves (16 arrivals each) -> root (16) -> gen.
// Producer: wave-wide s_waitcnt(0) drains this wave's sc0sc1 data stores to
// L3, then lane 0 runs the arrival chain. Each RMW result is consumed before
// the next op is issued -> same-thread HW ordering; gen bump implies all 256
// waves' data committed at L3. Consumers poll gen at L3; data is read with
// sc0sc1 loads (L3-direct), so no cache invalidate is needed. Lanes 1..63
// wait at exec-mask reconvergence of the lane-0 branch (single-wave: the
// whole wave executes the poll loop with exec={lane0}).
__device__ __forceinline__ void wave_group_barrier(unsigned* gbar, int lane, int leafIdx) {
  asm volatile("" ::: "memory");
  __builtin_amdgcn_s_waitcnt(0);  // drain this wave's stores (vm+lgkm)
  asm volatile("" ::: "memory");
  if (lane == 0) {
    unsigned* leaf = gbar + (leafIdx << 4);  // 16 leaves, 64 B apart
    unsigned* root = gbar + 256;             // byte 1024
    unsigned* gen  = gbar + 272;             // byte 1088
    unsigned g = __hip_atomic_load(gen, __ATOMIC_RELAXED, __HIP_MEMORY_SCOPE_AGENT);
    unsigned a = __hip_atomic_fetch_add(leaf, 1u, __ATOMIC_RELAXED, __HIP_MEMORY_SCOPE_AGENT);
    bool done = false;
    if ((a & 15u) == 15u) {
      unsigned b = __hip_atomic_fetch_add(root, 1u, __ATOMIC_RELAXED, __HIP_MEMORY_SCOPE_AGENT);
      if ((b & 15u) == 15u) {
        __hip_atomic_store(gen, g + 1u, __ATOMIC_RELAXED, __HIP_MEMORY_SCOPE_AGENT);
        done = true;
      }
    }
    if (!done) {
      while (__hip_atomic_load(gen, __ATOMIC_RELAXED, __HIP_MEMORY_SCOPE_AGENT) == g)
        __builtin_amdgcn_s_sleep(1);
    }
  }
  asm volatile("" ::: "memory");
}

__global__ __launch_bounds__(NT_, 2) void cfc_kernel(
    const float* __restrict__ x,    const float* __restrict__ ts,
    const float* __restrict__ h0,   const float* __restrict__ s0,
    const float* __restrict__ Wbb,  const float* __restrict__ bbb,
    const float* __restrict__ Wff1, const float* __restrict__ bff1,
    const float* __restrict__ Wff2, const float* __restrict__ bff2,
    const float* __restrict__ Wta,  const float* __restrict__ bta,
    const float* __restrict__ Wtb,  const float* __restrict__ btb,
    float* __restrict__ out, float* __restrict__ hws,
    float* __restrict__ bbws, unsigned* __restrict__ bar)
{
  __shared__ float part[8][16][66];   // 33792 B, wave-private slices, stride 66
  __shared__ float sums[8][64];       //  2048 B, wave-private slices

  const int tid  = threadIdx.x;
  const int wv   = tid >> 6;          // = group id 0..7
  const int lane = tid & 63;
  const int g8   = wv * 8;            // first batch row of this wave's group
  const int col0 = (int)blockIdx.x * 2;  // this wave's 2 output columns
  const int leafIdx = (int)(blockIdx.x >> 4);

  unsigned* gbar = bar + (wv << 9);   // 2 KB barrier region per group

  // ---- weights into registers (one-time; k = i*256 + lane*4 + e)
  float w1[2][3][4];
  #pragma unroll
  for (int c = 0; c < 2; ++c)
    #pragma unroll
    for (int i = 0; i < 3; ++i)
      #pragma unroll
      for (int e = 0; e < 4; ++e)
        w1[c][i][e] = Wbb[(size_t)(i * 256 + lane * 4 + e) * BU_ + (col0 + c)];

  float w2[4][2][2][4];
  const float* Wm[4] = {Wff1, Wff2, Wta, Wtb};
  #pragma unroll
  for (int m = 0; m < 4; ++m)
    #pragma unroll
    for (int c = 0; c < 2; ++c)
      #pragma unroll
      for (int i = 0; i < 2; ++i)
        #pragma unroll
        for (int e = 0; e < 4; ++e)
          w2[m][c][i][e] = Wm[m][(size_t)(i * 256 + lane * 4 + e) * H_ + (col0 + c)];

  float bb_b[2], fb1[2], fb2[2], fba[2], fbb2[2];
  #pragma unroll
  for (int c = 0; c < 2; ++c) {
    bb_b[c] = bbb[col0 + c];
    fb1[c]  = bff1[col0 + c];
    fb2[c]  = bff2[col0 + c];
    fba[c]  = bta[col0 + c];
    fbb2[c] = btb[col0 + c];
  }

  // s state in a register of lanes 0..15 (row rl=lane>>1, col c=lane&1)
  float sv = 0.f;
  if (lane < 16)
    sv = s0[(size_t)(g8 + (lane >> 1)) * H_ + col0 + (lane & 1)];

  // init this group's hws slice: wave wv writes its own rows, its 2 cols
  // (owner-writes only -> drained by THIS wave's barrier arrival).
  if (lane < 16) {
    const int row = g8 + (lane >> 1), c = lane & 1;
    astore(hws + (size_t)row * H_ + col0 + c, h0[(size_t)row * H_ + col0 + c]);
  }
  wave_group_barrier(gbar, lane, leafIdx);

  for (int t = 0; t < T_; ++t) {
    // ============ Phase 1: bb[g-rows, col0..+1] = silu(z @ Wbb + bbb) =======
    float p[16];
    #pragma unroll
    for (int o = 0; o < 16; ++o) p[o] = 0.f;

    #pragma unroll
    for (int r = 0; r < 8; ++r) {
      const int row = g8 + r;
      const float4 zx  = ((const float4*)(x + ((size_t)row * T_ + t) * D_))[lane];
      const float* hrow = hws + (size_t)row * H_;
      const float4 zh0 = aload4(hrow + lane * 4);
      const float4 zh1 = aload4(hrow + 256 + lane * 4);
      // Deferred coalesced out-write: block `row` owns out[row]; the wave
      // holding row (wv = row>>3) already has h(t-1)[row][:] across lanes.
      if (t > 0 && (int)blockIdx.x == row) {
        float4* op = (float4*)(out + ((size_t)row * T_ + (t - 1)) * H_);
        op[lane]      = zh0;
        op[lane + 64] = zh1;
      }
      #pragma unroll
      for (int c = 0; c < 2; ++c) {
        float a;
        a  = zx.x  * w1[c][0][0]; a += zx.y  * w1[c][0][1];
        a += zx.z  * w1[c][0][2]; a += zx.w  * w1[c][0][3];
        a += zh0.x * w1[c][1][0]; a += zh0.y * w1[c][1][1];
        a += zh0.z * w1[c][1][2]; a += zh0.w * w1[c][1][3];
        a += zh1.x * w1[c][2][0]; a += zh1.y * w1[c][2][1];
        a += zh1.z * w1[c][2][2]; a += zh1.w * w1[c][2][3];
        p[r * 2 + c] = a;
      }
    }

    #pragma unroll
    for (int o = 0; o < 16; ++o) part[wv][o][lane] = p[o];
    if (lane < 16) {
      const float2* pp = (const float2*)(&part[wv][lane][0]);
      float se = 0.f, so = 0.f;
      #pragma unroll
      for (int i = 0; i < 32; ++i) { float2 v = pp[i]; se += v.x; so += v.y; }
      const float pre = se + so + bb_b[lane & 1];
      const float bbv = pre * fsigmoid(pre);
      const int row = g8 + (lane >> 1);
      astore(bbws + (size_t)row * BU_ + col0 + (lane & 1), bbv);
    }
    wave_group_barrier(gbar, lane, leafIdx);  // group's bb at L3

    // ============ Phase 2: four mats + recurrence ============
    #pragma unroll
    for (int b = 0; b < 4; ++b) {
      float q[16];
      #pragma unroll
      for (int o = 0; o < 16; ++o) q[o] = 0.f;
      #pragma unroll
      for (int rr = 0; rr < 2; ++rr) {
        const int row = g8 + b * 2 + rr;
        const float* brow = bbws + (size_t)row * BU_;
        const float4 v0 = aload4(brow + lane * 4);
        const float4 v1 = aload4(brow + 256 + lane * 4);
        #pragma unroll
        for (int c = 0; c < 2; ++c)
          #pragma unroll
          for (int m = 0; m < 4; ++m) {
            float a;
            a  = v0.x * w2[m][c][0][0]; a += v0.y * w2[m][c][0][1];
            a += v0.z * w2[m][c][0][2]; a += v0.w * w2[m][c][0][3];
            a += v1.x * w2[m][c][1][0]; a += v1.y * w2[m][c][1][1];
            a += v1.z * w2[m][c][1][2]; a += v1.w * w2[m][c][1][3];
            q[rr * 8 + c * 4 + m] = a;
          }
      }
      #pragma unroll
      for (int o = 0; o < 16; ++o) part[wv][o][lane] = q[o];
      if (lane < 16) {
        const float2* pp = (const float2*)(&part[wv][lane][0]);
        float se = 0.f, so = 0.f;
        #pragma unroll
        for (int i = 0; i < 32; ++i) { float2 v = pp[i]; se += v.x; so += v.y; }
        sums[wv][b * 16 + lane] = se + so;
      }
    }

    if (lane < 16) {
      const int rl = lane >> 1, c = lane & 1;
      const int row = g8 + rl;
      const float4 Sm = *(const float4*)&sums[wv][(rl >> 1) * 16 + (rl & 1) * 8 + c * 4];
      const float tsv = ts[(size_t)row * T_ + t];
      const float tsn = 1.f / tsv;
      const float wts = __expf(tsn * (1.f - 2.f * __logf(tsn)));
      const float f1  = ftanh(Sm.x + fb1[c]);
      const float f2  = ftanh(Sm.y + fb2[c]);
      const float tav = Sm.z + fba[c];
      const float tbv = Sm.w + fbb2[c];
      sv += tav * wts + tbv;
      const float ti = fsigmoid(sv);
      const float hn = f1 + ti * (f2 - f1);
      astore(hws + (size_t)row * H_ + col0 + c, hn);
    }
    wave_group_barrier(gbar, lane, leafIdx);  // group's h at L3
  }

  // Tail: out[row, T-1, :] = h(T-1)[row]; written by the wave whose group
  // owns row=blockIdx (it just passed its own final h-barrier).
  if (blockIdx.x < 64 && wv == (int)(blockIdx.x >> 3)) {
    const int row = (int)blockIdx.x;
    const float* hrow = hws + (size_t)row * H_;
    const float4 a0 = aload4(hrow + lane * 4);
    const float4 a1 = aload4(hrow + 256 + lane * 4);
    float4* op = (float4*)(out + ((size_t)row * T_ + (T_ - 1)) * H_);
    op[lane]      = a0;
    op[lane + 64] = a1;
  }
}

extern "C" void kernel_launch(void* const* d_in, const int* in_sizes, int n_in,
                              void* d_out, int out_size, void* d_ws, size_t ws_size,
                              hipStream_t stream) {
  const float* x    = (const float*)d_in[0];
  const float* ts   = (const float*)d_in[1];
  const float* h0   = (const float*)d_in[2];
  const float* s0   = (const float*)d_in[3];
  const float* Wbb  = (const float*)d_in[4];
  const float* bbb  = (const float*)d_in[5];
  const float* Wff1 = (const float*)d_in[6];
  const float* bff1 = (const float*)d_in[7];
  const float* Wff2 = (const float*)d_in[8];
  const float* bff2 = (const float*)d_in[9];
  const float* Wta  = (const float*)d_in[10];
  const float* bta  = (const float*)d_in[11];
  const float* Wtb  = (const float*)d_in[12];
  const float* btb  = (const float*)d_in[13];
  float* out = (float*)d_out;

  // ws layout: [0,16384): 8 x 2KB group barrier regions; then h (128 KB);
  // then bb (128 KB).
  unsigned* bar = (unsigned*)d_ws;
  float* hws  = (float*)((char*)d_ws + 16384);
  float* bbws = hws + B_ * H_;

  hipMemsetAsync(d_ws, 0, 16384, stream);

  void* args[] = {
      (void*)&x, (void*)&ts, (void*)&h0, (void*)&s0,
      (void*)&Wbb, (void*)&bbb, (void*)&Wff1, (void*)&bff1,
      (void*)&Wff2, (void*)&bff2, (void*)&Wta, (void*)&bta,
      (void*)&Wtb, (void*)&btb, (void*)&out, (void*)&hws,
      (void*)&bbws, (void*)&bar};

  hipLaunchCooperativeKernel((const void*)cfc_kernel, dim3(GRID_), dim3(NT_),
                             args, 0, stream);
}

// Round 7
// 13498.720 us; speedup vs baseline: 3.2016x; 3.2016x over previous
//
#include <hip/hip_runtime.h>
#include <cstdint>
#include <cstddef>

#define B_    64
#define T_    1024
#define D_    256
#define H_    512
#define BU_   512
#define GRID_ 256
#define NT_   512
// 8 independent batch groups; group g = blocks with blockIdx%8==g.
// Each group: 32 blocks x (8 rows, 16 cols); per wave: 8 rows x 2 cols.
// Sync = flag-array barrier: arrival is ONE agent-scope store of the event id
// into the block's own slot (no RMW tree); detection is 32 lanes polling the
// 32 slots in parallel. Monotonic event ids: init=1, step t: bb=2t+2, h=2t+3.

__device__ __forceinline__ float fsigmoid(float x) { return 1.f / (1.f + __expf(-x)); }
__device__ __forceinline__ float ftanh(float x)    { return 2.f / (1.f + __expf(-2.f * x)) - 1.f; }

// Relaxed agent-scope atomic store: sc0/sc1 write-through, visible at L3 once
// vmcnt-drained, never dirty in any L2.
__device__ __forceinline__ void astore(float* p, float v) {
  union { float f; unsigned u; } c; c.f = v;
  __hip_atomic_store((unsigned*)p, c.u, __ATOMIC_RELAXED, __HIP_MEMORY_SCOPE_AGENT);
}
__device__ __forceinline__ void astore_u(unsigned* p, unsigned v) {
  __hip_atomic_store(p, v, __ATOMIC_RELAXED, __HIP_MEMORY_SCOPE_AGENT);
}
__device__ __forceinline__ unsigned aload_u(const unsigned* p) {
  return __hip_atomic_load(p, __ATOMIC_RELAXED, __HIP_MEMORY_SCOPE_AGENT);
}

// Relaxed agent-scope 8B atomic load: bypasses L1/L2, reads L3 directly ->
// always fresh, no buffer_inv needed anywhere.
__device__ __forceinline__ float2 aload2(const float* p) {
  unsigned long long u = __hip_atomic_load((const unsigned long long*)p,
                                           __ATOMIC_RELAXED, __HIP_MEMORY_SCOPE_AGENT);
  union { unsigned long long u; float2 f; } c; c.u = u;
  return c.f;
}
__device__ __forceinline__ float4 aload4(const float* p) {
  float2 a = aload2(p);
  float2 b = aload2(p + 2);
  return make_float4(a.x, a.y, b.x, b.y);
}

// Flag-array group barrier over 32 blocks, event id e (monotonic).
// Producer ordering: per-wave s_waitcnt(0) drains that wave's sc0sc1 data
// stores to L3; __syncthreads => ALL waves of the block drained; then tid 0
// stores e into this block's flag slot (sc0sc1, reaches L3). A consumer that
// observes flags[b] >= e therefore observes block b's data at L3.
// Detection: lanes 0..31 (wave 0) each poll one block's flag — one coalesced
// 128 B L3 load per round, lanes drop out as their producer arrives; second
// __syncthreads releases the block. Zero RMWs, no reset (monotonic ids),
// flag overwrite at e+1 is safe: waiters test >= e, and phase ordering
// prevents data WAR (a block reaches event e+1's stores only after every
// block passed event e's reads).
__device__ __forceinline__ void flag_barrier(unsigned* gflags, int glb,
                                             unsigned e, int tid) {
  asm volatile("" ::: "memory");
  __builtin_amdgcn_s_waitcnt(0);  // drain this wave's data stores (vm+lgkm)
  asm volatile("" ::: "memory");
  __syncthreads();                // all 8 waves drained
  if (tid == 0) astore_u(gflags + glb, e);
  asm volatile("" ::: "memory");  // pin store before poll (no compiler motion)
  if (tid < 32) {
    while (aload_u(gflags + tid) < e)
      __builtin_amdgcn_s_sleep(1);
  }
  __syncthreads();
}

__global__ __launch_bounds__(NT_, 2) void cfc_kernel(
    const float* __restrict__ x,    const float* __restrict__ ts,
    const float* __restrict__ h0,   const float* __restrict__ s0,
    const float* __restrict__ Wbb,  const float* __restrict__ bbb,
    const float* __restrict__ Wff1, const float* __restrict__ bff1,
    const float* __restrict__ Wff2, const float* __restrict__ bff2,
    const float* __restrict__ Wta,  const float* __restrict__ bta,
    const float* __restrict__ Wtb,  const float* __restrict__ btb,
    float* __restrict__ out, float* __restrict__ hws,
    float* __restrict__ bbws, unsigned* __restrict__ bar)
{
  __shared__ float part[8][16][66];   // 33792 B, stride 66 -> conflict-free
  __shared__ float sums[8][64];       //  2048 B
  __shared__ float sts[8][1028];      // 32896 B: group's ts rows, staged once

  const int tid  = threadIdx.x;
  const int wv   = tid >> 6;
  const int lane = tid & 63;
  const int g    = (int)(blockIdx.x & 7);   // group id (≈ XCD id)
  const int glb  = (int)(blockIdx.x >> 3);  // 0..31 within group
  const int g8   = g * 8;                   // first batch row of this group
  const int col0 = glb * 16 + wv * 2;       // this wave's 2 output columns

  unsigned* gflags = bar + (g << 6);        // 256 B flag region per group

  // ---- weights into registers (one-time; k = i*256 + lane*4 + e)
  float w1[2][3][4];
  #pragma unroll
  for (int c = 0; c < 2; ++c)
    #pragma unroll
    for (int i = 0; i < 3; ++i)
      #pragma unroll
      for (int e = 0; e < 4; ++e)
        w1[c][i][e] = Wbb[(size_t)(i * 256 + lane * 4 + e) * BU_ + (col0 + c)];

  float w2[4][2][2][4];
  const float* Wm[4] = {Wff1, Wff2, Wta, Wtb};
  #pragma unroll
  for (int m = 0; m < 4; ++m)
    #pragma unroll
    for (int c = 0; c < 2; ++c)
      #pragma unroll
      for (int i = 0; i < 2; ++i)
        #pragma unroll
        for (int e = 0; e < 4; ++e)
          w2[m][c][i][e] = Wm[m][(size_t)(i * 256 + lane * 4 + e) * H_ + (col0 + c)];

  float bb_b[2], fb1[2], fb2[2], fba[2], fbb2[2];
  #pragma unroll
  for (int c = 0; c < 2; ++c) {
    bb_b[c] = bbb[col0 + c];
    fb1[c]  = bff1[col0 + c];
    fb2[c]  = bff2[col0 + c];
    fba[c]  = bta[col0 + c];
    fbb2[c] = btb[col0 + c];
  }

  // s state lives in a register of lanes 0..15 (row rl=lane>>1, col c=lane&1)
  float sv = 0.f;
  if (lane < 16)
    sv = s0[(size_t)(g8 + (lane >> 1)) * H_ + col0 + (lane & 1)];

  // stage this group's ts rows into LDS (read every step, never changes)
  for (int i = tid; i < 8 * 1024; i += NT_)
    sts[i >> 10][i & 1023] = ts[(size_t)(g8 + (i >> 10)) * T_ + (i & 1023)];

  // init hws rows of this group (blocks glb<8 each own one row)
  if (glb < 8) {
    const int row = g8 + glb;
    astore(hws + (size_t)row * H_ + tid, h0[(size_t)row * H_ + tid]);
  }
  flag_barrier(gflags, glb, 1u, tid);   // event 1: h(init) at L3

  for (int t = 0; t < T_; ++t) {
    // ============ Phase 1: bb[g-rows, col0..+1] = silu(z @ Wbb + bbb) =======
    float p[16];
    #pragma unroll
    for (int o = 0; o < 16; ++o) p[o] = 0.f;

    #pragma unroll
    for (int r = 0; r < 8; ++r) {
      const int row = g8 + r;
      const float4 zx  = ((const float4*)(x + ((size_t)row * T_ + t) * D_))[lane];
      const float* hrow = hws + (size_t)row * H_;
      const float4 zh0 = aload4(hrow + lane * 4);
      const float4 zh1 = aload4(hrow + 256 + lane * 4);
      // Deferred coalesced out-write: group g's block glb==r owns out row
      // g8+r; wave 0 already holds h(t-1)[row][:] spread across lanes.
      if (t > 0 && r == glb && wv == 0) {
        float4* op = (float4*)(out + ((size_t)row * T_ + (t - 1)) * H_);
        op[lane]      = zh0;
        op[lane + 64] = zh1;
      }
      #pragma unroll
      for (int c = 0; c < 2; ++c) {
        float a;
        a  = zx.x  * w1[c][0][0]; a += zx.y  * w1[c][0][1];
        a += zx.z  * w1[c][0][2]; a += zx.w  * w1[c][0][3];
        a += zh0.x * w1[c][1][0]; a += zh0.y * w1[c][1][1];
        a += zh0.z * w1[c][1][2]; a += zh0.w * w1[c][1][3];
        a += zh1.x * w1[c][2][0]; a += zh1.y * w1[c][2][1];
        a += zh1.z * w1[c][2][2]; a += zh1.w * w1[c][2][3];
        p[r * 2 + c] = a;
      }
    }

    #pragma unroll
    for (int o = 0; o < 16; ++o) part[wv][o][lane] = p[o];
    if (lane < 16) {
      const float2* pp = (const float2*)(&part[wv][lane][0]);
      float se = 0.f, so = 0.f;
      #pragma unroll
      for (int i = 0; i < 32; ++i) { float2 v = pp[i]; se += v.x; so += v.y; }
      const float pre = se + so + bb_b[lane & 1];
      const float bbv = pre * fsigmoid(pre);
      const int row = g8 + (lane >> 1);
      astore(bbws + (size_t)row * BU_ + col0 + (lane & 1), bbv);
    }
    flag_barrier(gflags, glb, (unsigned)(2 * t + 2), tid);  // bb at L3

    // ============ Phase 2: four mats + recurrence ============
    #pragma unroll
    for (int b = 0; b < 4; ++b) {
      float q[16];
      #pragma unroll
      for (int o = 0; o < 16; ++o) q[o] = 0.f;
      #pragma unroll
      for (int rr = 0; rr < 2; ++rr) {
        const int row = g8 + b * 2 + rr;
        const float* brow = bbws + (size_t)row * BU_;
        const float4 v0 = aload4(brow + lane * 4);
        const float4 v1 = aload4(brow + 256 + lane * 4);
        #pragma unroll
        for (int c = 0; c < 2; ++c)
          #pragma unroll
          for (int m = 0; m < 4; ++m) {
            float a;
            a  = v0.x * w2[m][c][0][0]; a += v0.y * w2[m][c][0][1];
            a += v0.z * w2[m][c][0][2]; a += v0.w * w2[m][c][0][3];
            a += v1.x * w2[m][c][1][0]; a += v1.y * w2[m][c][1][1];
            a += v1.z * w2[m][c][1][2]; a += v1.w * w2[m][c][1][3];
            q[rr * 8 + c * 4 + m] = a;
          }
      }
      #pragma unroll
      for (int o = 0; o < 16; ++o) part[wv][o][lane] = q[o];
      if (lane < 16) {
        const float2* pp = (const float2*)(&part[wv][lane][0]);
        float se = 0.f, so = 0.f;
        #pragma unroll
        for (int i = 0; i < 32; ++i) { float2 v = pp[i]; se += v.x; so += v.y; }
        sums[wv][b * 16 + lane] = se + so;
      }
    }

    if (lane < 16) {
      const int rl = lane >> 1, c = lane & 1;
      const int row = g8 + rl;
      const float4 Sm = *(const float4*)&sums[wv][(rl >> 1) * 16 + (rl & 1) * 8 + c * 4];
      const float tsv = sts[rl][t];
      const float tsn = 1.f / tsv;
      const float wts = __expf(tsn * (1.f - 2.f * __logf(tsn)));
      const float f1  = ftanh(Sm.x + fb1[c]);
      const float f2  = ftanh(Sm.y + fb2[c]);
      const float tav = Sm.z + fba[c];
      const float tbv = Sm.w + fbb2[c];
      sv += tav * wts + tbv;
      const float ti = fsigmoid(sv);
      const float hn = f1 + ti * (f2 - f1);
      astore(hws + (size_t)row * H_ + col0 + c, hn);
    }
    flag_barrier(gflags, glb, (unsigned)(2 * t + 3), tid);  // h at L3
  }

  // Tail: out[row, T-1, :] = h(T-1)[row] for this group's rows (group-local
  // ownership: the final group barrier ordered these h writes).
  if (glb < 8 && wv == 0) {
    const int row = g8 + glb;
    const float* hrow = hws + (size_t)row * H_;
    const float4 a0 = aload4(hrow + lane * 4);
    const float4 a1 = aload4(hrow + 256 + lane * 4);
    float4* op = (float4*)(out + ((size_t)row * T_ + (T_ - 1)) * H_);
    op[lane]      = a0;
    op[lane + 64] = a1;
  }
}

extern "C" void kernel_launch(void* const* d_in, const int* in_sizes, int n_in,
                              void* d_out, int out_size, void* d_ws, size_t ws_size,
                              hipStream_t stream) {
  const float* x    = (const float*)d_in[0];
  const float* ts   = (const float*)d_in[1];
  const float* h0   = (const float*)d_in[2];
  const float* s0   = (const float*)d_in[3];
  const float* Wbb  = (const float*)d_in[4];
  const float* bbb  = (const float*)d_in[5];
  const float* Wff1 = (const float*)d_in[6];
  const float* bff1 = (const float*)d_in[7];
  const float* Wff2 = (const float*)d_in[8];
  const float* bff2 = (const float*)d_in[9];
  const float* Wta  = (const float*)d_in[10];
  const float* bta  = (const float*)d_in[11];
  const float* Wtb  = (const float*)d_in[12];
  const float* btb  = (const float*)d_in[13];
  float* out = (float*)d_out;

  // ws layout: [0,16384): 8 x 256B group flag regions (rest pad); then
  // h (128 KB); then bb (128 KB).
  unsigned* bar = (unsigned*)d_ws;
  float* hws  = (float*)((char*)d_ws + 16384);
  float* bbws = hws + B_ * H_;

  hipMemsetAsync(d_ws, 0, 16384, stream);

  void* args[] = {
      (void*)&x, (void*)&ts, (void*)&h0, (void*)&s0,
      (void*)&Wbb, (void*)&bbb, (void*)&Wff1, (void*)&bff1,
      (void*)&Wff2, (void*)&bff2, (void*)&Wta, (void*)&bta,
      (void*)&Wtb, (void*)&btb, (void*)&out, (void*)&hws,
      (void*)&bbws, (void*)&bar};

  hipLaunchCooperativeKernel((const void*)cfc_kernel, dim3(GRID_), dim3(NT_),
                             args, 0, stream);
}

// Round 8
// 10053.559 us; speedup vs baseline: 4.2988x; 1.3427x over previous
//
#include <hip/hip_runtime.h>
#include <cstdint>
#include <cstddef>

#define B_    64
#define T_    1024
#define D_    256
#define H_    512
#define BU_   512
#define GRID_ 256
#define NT_   512
// 8 independent batch groups; group g = blocks with blockIdx%8==g.
// Each group: 32 blocks x (8 rows, 16 cols); per wave: 8 rows x 2 cols.
// Sync = flag-array barrier (proven R7). NEW in R8: after each barrier the
// block stages the group's 16 KB exchange slice (h or bb) into LDS ONCE via
// 16B sc0sc1 loads, and all 8 waves consume from LDS -> ~16x fewer L3-direct
// transactions than per-wave 8B aloads.

__device__ __forceinline__ float fsigmoid(float x) { return 1.f / (1.f + __expf(-x)); }
__device__ __forceinline__ float ftanh(float x)    { return 2.f / (1.f + __expf(-2.f * x)) - 1.f; }

// Relaxed agent-scope atomic store: sc0/sc1 write-through, visible at L3 once
// vmcnt-drained, never dirty in any L2.
__device__ __forceinline__ void astore(float* p, float v) {
  union { float f; unsigned u; } c; c.f = v;
  __hip_atomic_store((unsigned*)p, c.u, __ATOMIC_RELAXED, __HIP_MEMORY_SCOPE_AGENT);
}
__device__ __forceinline__ void astore_u(unsigned* p, unsigned v) {
  __hip_atomic_store(p, v, __ATOMIC_RELAXED, __HIP_MEMORY_SCOPE_AGENT);
}
__device__ __forceinline__ unsigned aload_u(const unsigned* p) {
  return __hip_atomic_load(p, __ATOMIC_RELAXED, __HIP_MEMORY_SCOPE_AGENT);
}

// Relaxed agent-scope 8B atomic load (L3-direct). Used only for the tail.
__device__ __forceinline__ float2 aload2(const float* p) {
  unsigned long long u = __hip_atomic_load((const unsigned long long*)p,
                                           __ATOMIC_RELAXED, __HIP_MEMORY_SCOPE_AGENT);
  union { unsigned long long u; float2 f; } c; c.u = u;
  return c.f;
}
__device__ __forceinline__ float4 aload4(const float* p) {
  float2 a = aload2(p);
  float2 b = aload2(p + 2);
  return make_float4(a.x, a.y, b.x, b.y);
}

// Cooperative stage of a 4096-float (16 KB) global slice into LDS.
// 16B L3-coherent loads (sc0 sc1 = bypass L1/L2, read the coherence point —
// same cache-op bits the proven 8B agent atomics use, 2x wider). The wait is
// inside the same asm block as the loads, so the ds_writes' data dependence
// is safe. Trailing __syncthreads publishes LDS to all waves.
__device__ __forceinline__ void stage4k(const float* __restrict__ src,
                                        float* __restrict__ dst, int tid) {
  const float* p0 = src + tid * 4;
  const float* p1 = src + 2048 + tid * 4;
  float4 v0, v1;
  asm volatile(
      "global_load_dwordx4 %0, %2, off sc0 sc1\n\t"
      "global_load_dwordx4 %1, %3, off sc0 sc1\n\t"
      "s_waitcnt vmcnt(0)"
      : "=&v"(v0), "=&v"(v1)
      : "v"(p0), "v"(p1)
      : "memory");
  *(float4*)(dst + tid * 4) = v0;
  *(float4*)(dst + 2048 + tid * 4) = v1;
  __syncthreads();
}

// Flag-array group barrier over 32 blocks, event id e (monotonic) — proven R7.
__device__ __forceinline__ void flag_barrier(unsigned* gflags, int glb,
                                             unsigned e, int tid) {
  asm volatile("" ::: "memory");
  __builtin_amdgcn_s_waitcnt(0);  // drain this wave's data stores (vm+lgkm)
  asm volatile("" ::: "memory");
  __syncthreads();                // all 8 waves drained
  if (tid == 0) astore_u(gflags + glb, e);
  asm volatile("" ::: "memory");  // pin store before poll
  if (tid < 32) {
    while (aload_u(gflags + tid) < e)
      __builtin_amdgcn_s_sleep(1);
  }
  __syncthreads();
}

__global__ __launch_bounds__(NT_, 2) void cfc_kernel(
    const float* __restrict__ x,    const float* __restrict__ ts,
    const float* __restrict__ h0,   const float* __restrict__ s0,
    const float* __restrict__ Wbb,  const float* __restrict__ bbb,
    const float* __restrict__ Wff1, const float* __restrict__ bff1,
    const float* __restrict__ Wff2, const float* __restrict__ bff2,
    const float* __restrict__ Wta,  const float* __restrict__ bta,
    const float* __restrict__ Wtb,  const float* __restrict__ btb,
    float* __restrict__ out, float* __restrict__ hws,
    float* __restrict__ bbws, unsigned* __restrict__ bar)
{
  __shared__ float part[8][16][66];   // 33792 B, stride 66 -> conflict-free
  __shared__ float sums[8][64];       //  2048 B
  __shared__ float hbuf[4096];        // 16384 B: group h slice, staged/step
  __shared__ float bbuf[4096];        // 16384 B: group bb slice, staged/step

  const int tid  = threadIdx.x;
  const int wv   = tid >> 6;
  const int lane = tid & 63;
  const int g    = (int)(blockIdx.x & 7);   // group id (≈ XCD id)
  const int glb  = (int)(blockIdx.x >> 3);  // 0..31 within group
  const int g8   = g * 8;                   // first batch row of this group
  const int col0 = glb * 16 + wv * 2;       // this wave's 2 output columns

  unsigned* gflags = bar + (g << 6);        // 256 B flag region per group
  const float* hsl  = hws  + (size_t)g8 * H_;   // group h slice (4096 floats)
  const float* bbsl = bbws + (size_t)g8 * BU_;  // group bb slice (4096 floats)

  // ---- weights into registers (one-time; k = i*256 + lane*4 + e)
  float w1[2][3][4];
  #pragma unroll
  for (int c = 0; c < 2; ++c)
    #pragma unroll
    for (int i = 0; i < 3; ++i)
      #pragma unroll
      for (int e = 0; e < 4; ++e)
        w1[c][i][e] = Wbb[(size_t)(i * 256 + lane * 4 + e) * BU_ + (col0 + c)];

  float w2[4][2][2][4];
  const float* Wm[4] = {Wff1, Wff2, Wta, Wtb};
  #pragma unroll
  for (int m = 0; m < 4; ++m)
    #pragma unroll
    for (int c = 0; c < 2; ++c)
      #pragma unroll
      for (int i = 0; i < 2; ++i)
        #pragma unroll
        for (int e = 0; e < 4; ++e)
          w2[m][c][i][e] = Wm[m][(size_t)(i * 256 + lane * 4 + e) * H_ + (col0 + c)];

  float bb_b[2], fb1[2], fb2[2], fba[2], fbb2[2];
  #pragma unroll
  for (int c = 0; c < 2; ++c) {
    bb_b[c] = bbb[col0 + c];
    fb1[c]  = bff1[col0 + c];
    fb2[c]  = bff2[col0 + c];
    fba[c]  = bta[col0 + c];
    fbb2[c] = btb[col0 + c];
  }

  // s state lives in a register of lanes 0..15 (row rl=lane>>1, col c=lane&1)
  float sv = 0.f;
  if (lane < 16)
    sv = s0[(size_t)(g8 + (lane >> 1)) * H_ + col0 + (lane & 1)];

  // init hws rows of this group (blocks glb<8 each own one row)
  if (glb < 8) {
    const int row = g8 + glb;
    astore(hws + (size_t)row * H_ + tid, h0[(size_t)row * H_ + tid]);
  }
  flag_barrier(gflags, glb, 1u, tid);   // event 1: h(init) at L3

  for (int t = 0; t < T_; ++t) {
    // stage h(t-1) group slice -> LDS (once per block, 16B L3 loads)
    stage4k(hsl, hbuf, tid);

    // ============ Phase 1: bb[g-rows, col0..+1] = silu(z @ Wbb + bbb) =======
    float p[16];
    #pragma unroll
    for (int o = 0; o < 16; ++o) p[o] = 0.f;

    #pragma unroll
    for (int r = 0; r < 8; ++r) {
      const int row = g8 + r;
      const float4 zx  = ((const float4*)(x + ((size_t)row * T_ + t) * D_))[lane];
      const float4 zh0 = *(const float4*)&hbuf[r * 512 + lane * 4];
      const float4 zh1 = *(const float4*)&hbuf[r * 512 + 256 + lane * 4];
      // Deferred coalesced out-write: group g's block glb==r owns out row
      // g8+r; wave 0 holds h(t-1)[row][:] spread across lanes (from LDS).
      if (t > 0 && r == glb && wv == 0) {
        float4* op = (float4*)(out + ((size_t)row * T_ + (t - 1)) * H_);
        op[lane]      = zh0;
        op[lane + 64] = zh1;
      }
      #pragma unroll
      for (int c = 0; c < 2; ++c) {
        float a;
        a  = zx.x  * w1[c][0][0]; a += zx.y  * w1[c][0][1];
        a += zx.z  * w1[c][0][2]; a += zx.w  * w1[c][0][3];
        a += zh0.x * w1[c][1][0]; a += zh0.y * w1[c][1][1];
        a += zh0.z * w1[c][1][2]; a += zh0.w * w1[c][1][3];
        a += zh1.x * w1[c][2][0]; a += zh1.y * w1[c][2][1];
        a += zh1.z * w1[c][2][2]; a += zh1.w * w1[c][2][3];
        p[r * 2 + c] = a;
      }
    }

    #pragma unroll
    for (int o = 0; o < 16; ++o) part[wv][o][lane] = p[o];
    if (lane < 16) {
      const float2* pp = (const float2*)(&part[wv][lane][0]);
      float se = 0.f, so = 0.f;
      #pragma unroll
      for (int i = 0; i < 32; ++i) { float2 v = pp[i]; se += v.x; so += v.y; }
      const float pre = se + so + bb_b[lane & 1];
      const float bbv = pre * fsigmoid(pre);
      const int row = g8 + (lane >> 1);
      astore(bbws + (size_t)row * BU_ + col0 + (lane & 1), bbv);
    }
    flag_barrier(gflags, glb, (unsigned)(2 * t + 2), tid);  // bb at L3

    // stage bb group slice -> LDS (once per block)
    stage4k(bbsl, bbuf, tid);

    // ============ Phase 2: four mats + recurrence ============
    #pragma unroll
    for (int b = 0; b < 4; ++b) {
      float q[16];
      #pragma unroll
      for (int o = 0; o < 16; ++o) q[o] = 0.f;
      #pragma unroll
      for (int rr = 0; rr < 2; ++rr) {
        const int rloc = b * 2 + rr;
        const float4 v0 = *(const float4*)&bbuf[rloc * 512 + lane * 4];
        const float4 v1 = *(const float4*)&bbuf[rloc * 512 + 256 + lane * 4];
        #pragma unroll
        for (int c = 0; c < 2; ++c)
          #pragma unroll
          for (int m = 0; m < 4; ++m) {
            float a;
            a  = v0.x * w2[m][c][0][0]; a += v0.y * w2[m][c][0][1];
            a += v0.z * w2[m][c][0][2]; a += v0.w * w2[m][c][0][3];
            a += v1.x * w2[m][c][1][0]; a += v1.y * w2[m][c][1][1];
            a += v1.z * w2[m][c][1][2]; a += v1.w * w2[m][c][1][3];
            q[rr * 8 + c * 4 + m] = a;
          }
      }
      #pragma unroll
      for (int o = 0; o < 16; ++o) part[wv][o][lane] = q[o];
      if (lane < 16) {
        const float2* pp = (const float2*)(&part[wv][lane][0]);
        float se = 0.f, so = 0.f;
        #pragma unroll
        for (int i = 0; i < 32; ++i) { float2 v = pp[i]; se += v.x; so += v.y; }
        sums[wv][b * 16 + lane] = se + so;
      }
    }

    if (lane < 16) {
      const int rl = lane >> 1, c = lane & 1;
      const int row = g8 + rl;
      const float4 Sm = *(const float4*)&sums[wv][(rl >> 1) * 16 + (rl & 1) * 8 + c * 4];
      const float tsv = ts[(size_t)row * T_ + t];
      const float tsn = 1.f / tsv;
      const float wts = __expf(tsn * (1.f - 2.f * __logf(tsn)));
      const float f1  = ftanh(Sm.x + fb1[c]);
      const float f2  = ftanh(Sm.y + fb2[c]);
      const float tav = Sm.z + fba[c];
      const float tbv = Sm.w + fbb2[c];
      sv += tav * wts + tbv;
      const float ti = fsigmoid(sv);
      const float hn = f1 + ti * (f2 - f1);
      astore(hws + (size_t)row * H_ + col0 + c, hn);
    }
    flag_barrier(gflags, glb, (unsigned)(2 * t + 3), tid);  // h at L3
  }

  // Tail: out[row, T-1, :] = h(T-1)[row] for this group's rows (group-local
  // ownership: the final group barrier ordered these h writes).
  if (glb < 8 && wv == 0) {
    const int row = g8 + glb;
    const float* hrow = hws + (size_t)row * H_;
    const float4 a0 = aload4(hrow + lane * 4);
    const float4 a1 = aload4(hrow + 256 + lane * 4);
    float4* op = (float4*)(out + ((size_t)row * T_ + (T_ - 1)) * H_);
    op[lane]      = a0;
    op[lane + 64] = a1;
  }
}

extern "C" void kernel_launch(void* const* d_in, const int* in_sizes, int n_in,
                              void* d_out, int out_size, void* d_ws, size_t ws_size,
                              hipStream_t stream) {
  const float* x    = (const float*)d_in[0];
  const float* ts   = (const float*)d_in[1];
  const float* h0   = (const float*)d_in[2];
  const float* s0   = (const float*)d_in[3];
  const float* Wbb  = (const float*)d_in[4];
  const float* bbb  = (const float*)d_in[5];
  const float* Wff1 = (const float*)d_in[6];
  const float* bff1 = (const float*)d_in[7];
  const float* Wff2 = (const float*)d_in[8];
  const float* bff2 = (const float*)d_in[9];
  const float* Wta  = (const float*)d_in[10];
  const float* bta  = (const float*)d_in[11];
  const float* Wtb  = (const float*)d_in[12];
  const float* btb  = (const float*)d_in[13];
  float* out = (float*)d_out;

  // ws layout: [0,16384): 8 x 256B group flag regions (rest pad); then
  // h (128 KB); then bb (128 KB).
  unsigned* bar = (unsigned*)d_ws;
  float* hws  = (float*)((char*)d_ws + 16384);
  float* bbws = hws + B_ * H_;

  hipMemsetAsync(d_ws, 0, 16384, stream);

  void* args[] = {
      (void*)&x, (void*)&ts, (void*)&h0, (void*)&s0,
      (void*)&Wbb, (void*)&bbb, (void*)&Wff1, (void*)&bff1,
      (void*)&Wff2, (void*)&bff2, (void*)&Wta, (void*)&bta,
      (void*)&Wtb, (void*)&btb, (void*)&out, (void*)&hws,
      (void*)&bbws, (void*)&bar};

  hipLaunchCooperativeKernel((const void*)cfc_kernel, dim3(GRID_), dim3(NT_),
                             args, 0, stream);
}